// Round 2
// baseline (512.850 us; speedup 1.0000x reference)
//
#include <hip/hip_runtime.h>
#include <hip/hip_bf16.h>
#include <cstddef>

// ---------------- problem constants ----------------
#define BB   8
#define HH   120
#define WW   160
#define HW   19200          // HH*WW
#define NPIX 153600         // BB*HW
#define CORC 196

#define AS_  ((float)(6.0/127.0))   // ACT_SCALE
#define FS_  0.03125f               // FLOW_SCALE = 3.96875/127 = 2^-5 exactly

// ws float-offsets
#define OFF_WC1 16                  // [196][96] dequant fp32 (transposed)
#define OFF_WF1 18832               // [64][2]  dequant fp32
#define OFF_WF2 18960               // [64][32] dequant fp32 (transposed)
#define OFF_WD  21008               // [128][9] integer-valued fp32
#define OFF_WP  22160               // [128][80] integer-valued fp32 (transposed)
#define CFQ_BYTE_OFF 131072         // int8 activation buffer, 8*128*19200 bytes

__device__ __forceinline__ float clip127(float x) {
    return fminf(fmaxf(x, -127.f), 127.f);
}

// ---------------- kernel 0: weight fake-quant ----------------
__global__ __launch_bounds__(256) void quant_weights(
    const float* __restrict__ Wc1, const float* __restrict__ Wf1,
    const float* __restrict__ Wf2, const float* __restrict__ Wd,
    const float* __restrict__ Wp,  float* __restrict__ ws)
{
    __shared__ float red[256];
    const int t = blockIdx.x;
    const float* src = (t == 0) ? Wc1 : (t == 1) ? Wf1 : (t == 2) ? Wf2 : (t == 3) ? Wd : Wp;
    const int n = (t == 0) ? 18816 : (t == 1) ? 128 : (t == 2) ? 2048 : (t == 3) ? 1152 : 10240;
    const int tid = threadIdx.x;

    float m = 0.f;
    for (int i = tid; i < n; i += 256) m = fmaxf(m, fabsf(src[i]));
    red[tid] = m;
    __syncthreads();
    for (int s = 128; s > 0; s >>= 1) {
        if (tid < s) red[tid] = fmaxf(red[tid], red[tid + s]);
        __syncthreads();
    }
    const float s = red[0] / 127.0f + 1e-12f;

    for (int i = tid; i < n; i += 256) {
        const float q = clip127(rintf(src[i] / s));
        if (t == 0) {            // Wc1 [96][196] -> transposed dequant [196][96]
            int o = i / 196, c = i % 196;
            ws[OFF_WC1 + c * 96 + o] = s * q;
        } else if (t == 1) {     // Wf1 [64][2]
            ws[OFF_WF1 + i] = s * q;
        } else if (t == 2) {     // Wf2 [32][64] -> transposed [64][32]
            int o = i / 64, c = i % 64;
            ws[OFF_WF2 + c * 32 + o] = s * q;
        } else if (t == 3) {     // Wd [128][9]: keep integer q
            ws[OFF_WD + i] = q;
        } else {                 // Wp [80][128] -> transposed integer q [128][80]
            int o = i / 128, c = i % 128;
            ws[OFF_WP + c * 80 + o] = q;
        }
    }
    if (tid == 0) {
        if (t == 3) ws[0] = s;   // depthwise scale
        if (t == 4) ws[1] = s;   // pointwise scale
    }
}

// ---------------- kernel 1a: convc1 (196 -> 96), spill-free chunked ----------------
// block = 256 threads = 128 pixels x 2 output-chunks of 48.
// chunk = tid/128 is wave-uniform -> weight loads stay scalar;
// pixels are consecutive within a wave -> corr loads coalesced.
__global__ __launch_bounds__(256) void k1_convc1(
    const float* __restrict__ corr, const float* __restrict__ bc1,
    const float* __restrict__ ws,   signed char* __restrict__ cfq)
{
    const int tid   = threadIdx.x;
    const int chunk = tid >> 7;          // 0 or 1 (wave-uniform)
    const int pxl   = tid & 127;
    const int p     = blockIdx.x * 128 + pxl;   // 19200 % 128 == 0 -> no b straddle
    const int b     = p / HW;
    const int hw    = p % HW;

    const float* cp = corr + (size_t)b * CORC * HW + hw;
    const float* wc = ws + OFF_WC1 + chunk * 48;

    float acc[48];
#pragma unroll
    for (int o = 0; o < 48; ++o) acc[o] = 0.f;

    for (int c = 0; c < CORC; ++c) {
        const float a = cp[(size_t)c * HW];
        const float* w = wc + c * 96;    // wave-uniform -> scalar loads
#pragma unroll
        for (int o = 0; o < 48; ++o) acc[o] = fmaf(a, w[o], acc[o]);
    }

    signed char* op = cfq + (size_t)b * 128 * HW + (size_t)(chunk * 48) * HW + hw;
#pragma unroll
    for (int o = 0; o < 48; ++o) {
        float v  = acc[o] + bc1[chunk * 48 + o];
        float aq = AS_ * clip127(rintf(v / AS_));   // act_quant(., ACT)
        float r  = fmaxf(aq, 0.f);                  // relu
        float k  = fminf(rintf(r * 32.f), 127.f);   // act_quant(., FLOW): /FS == *32 exact
        float cf = k * FS_;                         // exact; outer cat-quant is identity
        float q8 = clip127(rintf(cf / AS_));        // act_quant(cf, ACT) -> int code
        op[(size_t)o * HW] = (signed char)(int)q8;
    }
}

// ---------------- kernel 1b: flo path (convf1 2->64, convf2 64->32) ----------------
__global__ __launch_bounds__(256) void k1_flo(
    const float* __restrict__ flow, const float* __restrict__ bf1,
    const float* __restrict__ bf2,  const float* __restrict__ ws,
    signed char* __restrict__ cfq)
{
    const int p  = blockIdx.x * 256 + threadIdx.x;
    const int b  = p / HW;
    const int hw = p % HW;

    const float f0 = flow[(size_t)(b * 2) * HW + hw];
    const float f1 = flow[(size_t)(b * 2 + 1) * HW + hw];
    float af[64];
#pragma unroll
    for (int o = 0; o < 64; ++o) {
        float v  = f0 * ws[OFF_WF1 + 2 * o] + f1 * ws[OFF_WF1 + 2 * o + 1] + bf1[o];
        float r  = fmaxf(v, 0.f);
        float qf = fminf(rintf(r / AS_), 127.f);    // r >= 0
        af[o] = AS_ * qf;
    }

    float a2[32];
#pragma unroll
    for (int o = 0; o < 32; ++o) a2[o] = 0.f;
    for (int c = 0; c < 64; ++c) {
        const float a = af[c];
        const float* w = ws + OFF_WF2 + c * 32;
#pragma unroll
        for (int o = 0; o < 32; ++o) a2[o] = fmaf(a, w[o], a2[o]);
    }

    signed char* op = cfq + (size_t)b * 128 * HW + (size_t)96 * HW + hw;
#pragma unroll
    for (int o = 0; o < 32; ++o) {
        float v  = a2[o] + bf2[o];
        float aq = AS_ * clip127(rintf(v / AS_));
        float r  = fmaxf(aq, 0.f);
        float k  = fminf(rintf(r * 32.f), 127.f);
        float cf = k * FS_;
        float q8 = clip127(rintf(cf / AS_));
        op[(size_t)o * HW] = (signed char)(int)q8;
    }
}

// ---------------- kernel 2: depthwise 3x3 + pointwise + final quant-cat ----------------
__global__ __launch_bounds__(256) void k2_dwpw(
    const float* __restrict__ flow, const float* __restrict__ bd,
    const float* __restrict__ bp,   const float* __restrict__ ws,
    const signed char* __restrict__ cfq, float* __restrict__ out)
{
    __shared__ unsigned int lds[12800];   // 10 rows * 128 ch * 40 bytes
    const int bid = blockIdx.x;
    const int b  = bid / 75;
    const int rem = bid % 75;
    const int h0 = (rem / 5) * 8;
    const int w0 = (rem % 5) * 32;

    for (int j = threadIdx.x; j < 12800; j += 256) {
        const int i   = j % 10;
        const int c   = (j / 10) % 128;
        const int row = j / 1280;
        const int h   = h0 - 1 + row;
        const int wb  = w0 - 4 + 4 * i;
        unsigned int v = 0u;
        if (h >= 0 && h < HH && wb >= 0 && wb <= WW - 4)
            v = *(const unsigned int*)(cfq + ((size_t)(b * 128 + c) * HW + (size_t)h * WW + wb));
        lds[(row * 128 + c) * 10 + i] = v;
    }
    __syncthreads();

    const int tx = threadIdx.x % 32;
    const int ty = threadIdx.x / 32;
    const signed char* lds8 = (const signed char*)lds;

    const float sd   = ws[0];
    const float sp   = ws[1];
    const float ASsd = AS_ * sd;
    const float ASsp = AS_ * sp;

    float accp[80];
#pragma unroll
    for (int o = 0; o < 80; ++o) accp[o] = 0.f;

    for (int c = 0; c < 128; ++c) {
        float s = 0.f;
#pragma unroll
        for (int dy = 0; dy < 3; ++dy) {
            const int base = ((ty + dy) * 128 + c) * 40 + tx + 3;
#pragma unroll
            for (int dd = 0; dd < 3; ++dd) {
                const float a = (float)lds8[base + dd];
                s = fmaf(a, ws[OFF_WD + c * 9 + dy * 3 + dd], s);
            }
        }
        const float d  = fmaf(ASsd, s, bd[c]);
        const float q2 = clip127(rintf(d / AS_));     // act_quant(d, ACT) int code
        const float* w = ws + OFF_WP + c * 80;        // uniform -> scalar loads
#pragma unroll
        for (int o = 0; o < 80; ++o) accp[o] = fmaf(q2, w[o], accp[o]);
    }

    const int h  = h0 + ty;
    const int w  = w0 + tx;
    const int hw = h * WW + w;
    float* opx = out + (size_t)b * 82 * HW + hw;
#pragma unroll
    for (int o = 0; o < 80; ++o) {
        float v = fmaf(ASsp, accp[o], bp[o]);
        float r = fmaxf(v, 0.f);
        float k = fminf(rintf(r * 32.f), 127.f);
        opx[(size_t)o * HW] = k * FS_;
    }
#pragma unroll
    for (int j = 0; j < 2; ++j) {
        float f = flow[(size_t)(b * 2 + j) * HW + hw];
        float k = clip127(rintf(f * 32.f));
        opx[(size_t)(80 + j) * HW] = k * FS_;
    }
}

// ---------------- launcher ----------------
extern "C" void kernel_launch(void* const* d_in, const int* in_sizes, int n_in,
                              void* d_out, int out_size, void* d_ws, size_t ws_size,
                              hipStream_t stream) {
    const float* flow = (const float*)d_in[0];
    const float* corr = (const float*)d_in[1];
    const float* Wc1  = (const float*)d_in[2];
    const float* bc1  = (const float*)d_in[3];
    const float* Wf1  = (const float*)d_in[4];
    const float* bf1  = (const float*)d_in[5];
    const float* Wf2  = (const float*)d_in[6];
    const float* bf2  = (const float*)d_in[7];
    const float* Wd   = (const float*)d_in[8];
    const float* bd   = (const float*)d_in[9];
    const float* Wp   = (const float*)d_in[10];
    const float* bp   = (const float*)d_in[11];

    float* ws = (float*)d_ws;
    signed char* cfq = (signed char*)d_ws + CFQ_BYTE_OFF;
    float* out = (float*)d_out;

    quant_weights<<<5, 256, 0, stream>>>(Wc1, Wf1, Wf2, Wd, Wp, ws);
    k1_convc1<<<NPIX / 128, 256, 0, stream>>>(corr, bc1, ws, cfq);
    k1_flo<<<NPIX / 256, 256, 0, stream>>>(flow, bf1, bf2, ws, cfq);
    k2_dwpw<<<600, 256, 0, stream>>>(flow, bd, bp, ws, cfq, out);
}

// Round 3
// 219.672 us; speedup vs baseline: 2.3346x; 2.3346x over previous
//
#include <hip/hip_runtime.h>
#include <hip/hip_bf16.h>
#include <cstddef>

// ---------------- problem constants ----------------
#define BB   8
#define HH   120
#define WW   160
#define HW   19200          // HH*WW
#define NPIX 153600         // BB*HW
#define CORC 196

#define AS_  ((float)(6.0/127.0))   // ACT_SCALE
#define FS_  0.03125f               // FLOW_SCALE = 3.96875/127 = 2^-5 exactly

// ws layout:
//   float[0] = sd (depthwise scale), float[1] = sp (pointwise scale), float[2] = s_c1 (convc1 scale)
//   ushort[32 .. 32+21504) : convc1 B-fragments, bf16 integer codes, fragment-ordered
//   float[OFF_WF1 ..] etc. as below
#define OFF_WF1 18832               // [64][2]  dequant fp32
#define OFF_WF2 18960               // [64][32] dequant fp32 (transposed)
#define OFF_WD  21008               // [128][9] integer-valued fp32
#define OFF_WP  22160               // [128][80] integer-valued fp32 (transposed)
#define CFQ_BYTE_OFF 131072         // int8 activation buffer, 8*128*19200 bytes

typedef __attribute__((ext_vector_type(8)))  short short8;
typedef __attribute__((ext_vector_type(4)))  float f32x4;
typedef __attribute__((ext_vector_type(16))) float f32x16;

__device__ __forceinline__ float clip127(float x) {
    return fminf(fmaxf(x, -127.f), 127.f);
}

// round-to-nearest-even fp32 -> bf16 (finite inputs only)
__device__ __forceinline__ unsigned short f2bf(float x) {
    unsigned int u = __float_as_uint(x);
    unsigned int r = (u + 0x7fffu + ((u >> 16) & 1u)) >> 16;
    return (unsigned short)r;
}

// ---------------- kernel 0: weight fake-quant ----------------
__global__ __launch_bounds__(256) void quant_weights(
    const float* __restrict__ Wc1, const float* __restrict__ Wf1,
    const float* __restrict__ Wf2, const float* __restrict__ Wd,
    const float* __restrict__ Wp,  float* __restrict__ ws)
{
    __shared__ float red[256];
    const int t = blockIdx.x;
    const float* src = (t == 0) ? Wc1 : (t == 1) ? Wf1 : (t == 2) ? Wf2 : (t == 3) ? Wd : Wp;
    const int n = (t == 0) ? 18816 : (t == 1) ? 128 : (t == 2) ? 2048 : (t == 3) ? 1152 : 10240;
    const int tid = threadIdx.x;

    float m = 0.f;
    for (int i = tid; i < n; i += 256) m = fmaxf(m, fabsf(src[i]));
    red[tid] = m;
    __syncthreads();
    for (int s = 128; s > 0; s >>= 1) {
        if (tid < s) red[tid] = fmaxf(red[tid], red[tid + s]);
        __syncthreads();
    }
    const float s = red[0] / 127.0f + 1e-12f;

    if (t == 0) {
        // pack convc1 weights as MFMA B-fragments (bf16 integer codes).
        // frag element j = ((kt*6 + nt)*64 + lane)*8 + e
        //   out = nt*16 + (lane&15),  k = kt*32 + (lane>>4)*8 + e,  0 if k >= 196
        unsigned short* bf = (unsigned short*)ws + 32;
        for (int j = tid; j < 21504; j += 256) {
            const int e    = j & 7;
            const int l    = (j >> 3) & 63;
            const int tile = j >> 9;
            const int nt   = tile % 6;
            const int kt   = tile / 6;
            const int out  = nt * 16 + (l & 15);
            const int k    = kt * 32 + ((l >> 4) << 3) + e;
            float q = 0.f;
            if (k < 196) q = clip127(rintf(Wc1[out * 196 + k] / s));
            bf[j] = f2bf(q);
        }
        if (tid == 0) ws[2] = s;
    } else {
        for (int i = tid; i < n; i += 256) {
            const float q = clip127(rintf(src[i] / s));
            if (t == 1) {            // Wf1 [64][2]
                ws[OFF_WF1 + i] = s * q;
            } else if (t == 2) {     // Wf2 [32][64] -> transposed [64][32]
                int o = i / 64, c = i % 64;
                ws[OFF_WF2 + c * 32 + o] = s * q;
            } else if (t == 3) {     // Wd [128][9]: keep integer q
                ws[OFF_WD + i] = q;
            } else {                 // Wp [80][128] -> transposed integer q [128][80]
                int o = i / 128, c = i % 128;
                ws[OFF_WP + c * 80 + o] = q;
            }
        }
        if (tid == 0) {
            if (t == 3) ws[0] = s;
            if (t == 4) ws[1] = s;
        }
    }
}

// ---------------- kernel 1a: convc1 (196 -> 96) via bf16 MFMA ----------------
// block = 256 threads = 4 waves; 64 pixels per block, each wave owns 16 pixels x 96 outs.
// A = activations split hi+lo bf16 in LDS [64][232]; B = integer-code frags from ws.
#define LDSTRIDE 232
__global__ __launch_bounds__(256) void k1_convc1(
    const float* __restrict__ corr, const float* __restrict__ bc1,
    const float* __restrict__ ws,   signed char* __restrict__ cfq)
{
    __shared__ unsigned short hbuf[64 * LDSTRIDE];
    __shared__ unsigned short lbuf[64 * LDSTRIDE];

    const int tid = threadIdx.x;
    const int p0  = blockIdx.x * 64;          // 19200 % 64 == 0 -> no batch straddle
    const int b   = p0 / HW;
    const int hw0 = p0 % HW;
    const float* cp = corr + (size_t)b * CORC * HW + hw0;

    // ---- stage: fp32 corr -> (hi, lo) bf16 in LDS ----
    const int pix  = tid & 63;
    const int cgrp = tid >> 6;
    unsigned short* hrow = hbuf + pix * LDSTRIDE;
    unsigned short* lrow = lbuf + pix * LDSTRIDE;

    for (int iter = 0; iter < 13; ++iter) {
        const int c0 = iter * 16 + cgrp * 4;
        unsigned long long hp = 0ull, lp = 0ull;
#pragma unroll
        for (int j = 0; j < 4; ++j) {
            const int c = c0 + j;
            float a = 0.f;
            if (c < 196) a = cp[(size_t)c * HW + pix];
            const unsigned short h = f2bf(a);
            const float hf = __uint_as_float((unsigned int)h << 16);
            const unsigned short lo = f2bf(a - hf);
            hp |= (unsigned long long)h  << (16 * j);
            lp |= (unsigned long long)lo << (16 * j);
        }
        *(unsigned long long*)(hrow + c0) = hp;
        *(unsigned long long*)(lrow + c0) = lp;
    }
    {   // zero pad k = 208..223
        const int c0z = 208 + cgrp * 4;
        *(unsigned long long*)(hrow + c0z) = 0ull;
        *(unsigned long long*)(lrow + c0z) = 0ull;
    }
    __syncthreads();

    // ---- compute: 7 K-steps x 6 N-tiles x (hi+lo) MFMA ----
    const int w = tid >> 6;        // wave id (uniform)
    const int l = tid & 63;        // lane
    const int arow = w * 16 + (l & 15);
    const int koff = (l >> 4) << 3;
    const unsigned short* hA = hbuf + arow * LDSTRIDE + koff;
    const unsigned short* lA = lbuf + arow * LDSTRIDE + koff;
    const short8* Bfr = (const short8*)((const unsigned short*)ws + 32);

    f32x4 ac0 = {0.f,0.f,0.f,0.f}, ac1 = ac0, ac2 = ac0, ac3 = ac0, ac4 = ac0, ac5 = ac0;

#define NTSTEP(ACC, KT, NT)                                                      \
    {   short8 bq = Bfr[((KT) * 6 + (NT)) * 64 + l];                             \
        ACC = __builtin_amdgcn_mfma_f32_16x16x32_bf16(al_, bq, ACC, 0, 0, 0);    \
        ACC = __builtin_amdgcn_mfma_f32_16x16x32_bf16(ah_, bq, ACC, 0, 0, 0);    }

#pragma unroll
    for (int kt = 0; kt < 7; ++kt) {
        short8 ah_ = *(const short8*)(hA + kt * 32);
        short8 al_ = *(const short8*)(lA + kt * 32);
        NTSTEP(ac0, kt, 0) NTSTEP(ac1, kt, 1) NTSTEP(ac2, kt, 2)
        NTSTEP(ac3, kt, 3) NTSTEP(ac4, kt, 4) NTSTEP(ac5, kt, 5)
    }
#undef NTSTEP

    // ---- epilogue: quant chain, transpose via LDS, coalesced store ----
    const float sc1 = ws[2];
    __syncthreads();                       // done reading hbuf/lbuf
    signed char* t8 = (signed char*)hbuf;  // reuse as [96][64] int8

#define EPI(ACC, NT)                                                             \
    {   const int out = (NT) * 16 + (l & 15);                                    \
        const float bias = bc1[out];                                             \
        _Pragma("unroll")                                                        \
        for (int i = 0; i < 4; ++i) {                                            \
            const int prow = w * 16 + ((l >> 4) << 2) + i;                       \
            float v  = fmaf(sc1, ACC[i], bias);                                  \
            float aq = AS_ * clip127(rintf(v / AS_));                            \
            float r  = fmaxf(aq, 0.f);                                           \
            float kk = fminf(rintf(r * 32.f), 127.f);                            \
            float cf = kk * FS_;                                                 \
            float q8 = clip127(rintf(cf / AS_));                                 \
            t8[out * 64 + prow] = (signed char)(int)q8;                          \
        }                                                                        }
    EPI(ac0, 0) EPI(ac1, 1) EPI(ac2, 2) EPI(ac3, 3) EPI(ac4, 4) EPI(ac5, 5)
#undef EPI
    __syncthreads();

    const unsigned int* t32 = (const unsigned int*)t8;
#pragma unroll
    for (int r = 0; r < 6; ++r) {
        const int d   = r * 256 + tid;     // d == out*16 + pixdw
        const int out = d >> 4;
        const int pd  = d & 15;
        *(unsigned int*)(cfq + (size_t)(b * 128 + out) * HW + hw0 + pd * 4) = t32[d];
    }
}

// ---------------- kernel 1b: flo path (convf1 2->64, convf2 64->32) ----------------
__global__ __launch_bounds__(256) void k1_flo(
    const float* __restrict__ flow, const float* __restrict__ bf1,
    const float* __restrict__ bf2,  const float* __restrict__ ws,
    signed char* __restrict__ cfq)
{
    const int p  = blockIdx.x * 256 + threadIdx.x;
    const int b  = p / HW;
    const int hw = p % HW;

    const float f0 = flow[(size_t)(b * 2) * HW + hw];
    const float f1 = flow[(size_t)(b * 2 + 1) * HW + hw];

    f32x16 a2a, a2b;
#pragma unroll
    for (int j = 0; j < 16; ++j) { a2a[j] = 0.f; a2b[j] = 0.f; }

    for (int c = 0; c < 64; ++c) {
        const float w0 = ws[OFF_WF1 + 2 * c];
        const float w1 = ws[OFF_WF1 + 2 * c + 1];
        float v  = fmaf(f0, w0, fmaf(f1, w1, bf1[c]));
        float r  = fmaxf(v, 0.f);
        float af = AS_ * fminf(rintf(r / AS_), 127.f);
        const float* w2 = ws + OFF_WF2 + c * 32;
#pragma unroll
        for (int j = 0; j < 16; ++j) {
            a2a[j] = fmaf(af, w2[j],      a2a[j]);
            a2b[j] = fmaf(af, w2[16 + j], a2b[j]);
        }
    }

    signed char* op = cfq + (size_t)b * 128 * HW + (size_t)96 * HW + hw;
#define FLOEPI(ACC, BASE)                                                        \
    _Pragma("unroll")                                                            \
    for (int j = 0; j < 16; ++j) {                                               \
        const int o = (BASE) + j;                                                \
        float v  = ACC[j] + bf2[o];                                              \
        float aq = AS_ * clip127(rintf(v / AS_));                                \
        float r  = fmaxf(aq, 0.f);                                               \
        float kk = fminf(rintf(r * 32.f), 127.f);                                \
        float cf = kk * FS_;                                                     \
        float q8 = clip127(rintf(cf / AS_));                                     \
        op[(size_t)o * HW] = (signed char)(int)q8;                               \
    }
    FLOEPI(a2a, 0) FLOEPI(a2b, 16)
#undef FLOEPI
}

// ---------------- kernel 2: depthwise 3x3 + pointwise + final quant-cat ----------------
__global__ __launch_bounds__(256) void k2_dwpw(
    const float* __restrict__ flow, const float* __restrict__ bd,
    const float* __restrict__ bp,   const float* __restrict__ ws,
    const signed char* __restrict__ cfq, float* __restrict__ out)
{
    __shared__ unsigned int lds[12800];   // 10 rows * 128 ch * 40 bytes
    const int bid = blockIdx.x;
    const int b   = bid / 75;
    const int rem = bid % 75;
    const int h0  = (rem / 5) * 8;
    const int w0  = (rem % 5) * 32;

    for (int j = threadIdx.x; j < 12800; j += 256) {
        const int i   = j % 10;
        const int c   = (j / 10) % 128;
        const int row = j / 1280;
        const int h   = h0 - 1 + row;
        const int wb  = w0 - 4 + 4 * i;
        unsigned int v = 0u;
        if (h >= 0 && h < HH && wb >= 0 && wb <= WW - 4)
            v = *(const unsigned int*)(cfq + ((size_t)(b * 128 + c) * HW + (size_t)h * WW + wb));
        lds[(row * 128 + c) * 10 + i] = v;
    }
    __syncthreads();

    const int tx = threadIdx.x % 32;
    const int ty = threadIdx.x / 32;
    const signed char* lds8 = (const signed char*)lds;

    const float sd   = ws[0];
    const float sp   = ws[1];
    const float ASsd = AS_ * sd;
    const float ASsp = AS_ * sp;

    f32x16 ap0, ap1, ap2, ap3, ap4;
#pragma unroll
    for (int j = 0; j < 16; ++j) { ap0[j]=0.f; ap1[j]=0.f; ap2[j]=0.f; ap3[j]=0.f; ap4[j]=0.f; }

    for (int c = 0; c < 128; ++c) {
        float s = 0.f;
#pragma unroll
        for (int dy = 0; dy < 3; ++dy) {
            const int base = ((ty + dy) * 128 + c) * 40 + tx + 3;
#pragma unroll
            for (int dd = 0; dd < 3; ++dd) {
                const float a = (float)lds8[base + dd];
                s = fmaf(a, ws[OFF_WD + c * 9 + dy * 3 + dd], s);
            }
        }
        const float d  = fmaf(ASsd, s, bd[c]);
        const float q2 = clip127(rintf(d / AS_));     // act_quant(d, ACT) int code
        const float* wp = ws + OFF_WP + c * 80;       // uniform -> scalar loads
#pragma unroll
        for (int j = 0; j < 16; ++j) {
            ap0[j] = fmaf(q2, wp[j],      ap0[j]);
            ap1[j] = fmaf(q2, wp[16 + j], ap1[j]);
            ap2[j] = fmaf(q2, wp[32 + j], ap2[j]);
            ap3[j] = fmaf(q2, wp[48 + j], ap3[j]);
            ap4[j] = fmaf(q2, wp[64 + j], ap4[j]);
        }
    }

    const int h  = h0 + ty;
    const int w  = w0 + tx;
    const int hw = h * WW + w;
    float* opx = out + (size_t)b * 82 * HW + hw;

#define K2EPI(ACC, BASE)                                                         \
    _Pragma("unroll")                                                            \
    for (int j = 0; j < 16; ++j) {                                               \
        const int o = (BASE) + j;                                                \
        float v = fmaf(ASsp, ACC[j], bp[o]);                                     \
        float r = fmaxf(v, 0.f);                                                 \
        float k = fminf(rintf(r * 32.f), 127.f);                                 \
        opx[(size_t)o * HW] = k * FS_;                                           \
    }
    K2EPI(ap0, 0) K2EPI(ap1, 16) K2EPI(ap2, 32) K2EPI(ap3, 48) K2EPI(ap4, 64)
#undef K2EPI

#pragma unroll
    for (int j = 0; j < 2; ++j) {
        float f = flow[(size_t)(b * 2 + j) * HW + hw];
        float k = clip127(rintf(f * 32.f));
        opx[(size_t)(80 + j) * HW] = k * FS_;
    }
}

// ---------------- launcher ----------------
extern "C" void kernel_launch(void* const* d_in, const int* in_sizes, int n_in,
                              void* d_out, int out_size, void* d_ws, size_t ws_size,
                              hipStream_t stream) {
    const float* flow = (const float*)d_in[0];
    const float* corr = (const float*)d_in[1];
    const float* Wc1  = (const float*)d_in[2];
    const float* bc1  = (const float*)d_in[3];
    const float* Wf1  = (const float*)d_in[4];
    const float* bf1  = (const float*)d_in[5];
    const float* Wf2  = (const float*)d_in[6];
    const float* bf2  = (const float*)d_in[7];
    const float* Wd   = (const float*)d_in[8];
    const float* bd   = (const float*)d_in[9];
    const float* Wp   = (const float*)d_in[10];
    const float* bp   = (const float*)d_in[11];

    float* ws = (float*)d_ws;
    signed char* cfq = (signed char*)d_ws + CFQ_BYTE_OFF;
    float* out = (float*)d_out;

    quant_weights<<<5, 256, 0, stream>>>(Wc1, Wf1, Wf2, Wd, Wp, ws);
    k1_convc1<<<NPIX / 64, 256, 0, stream>>>(corr, bc1, ws, cfq);
    k1_flo<<<NPIX / 256, 256, 0, stream>>>(flow, bf1, bf2, ws, cfq);
    k2_dwpw<<<600, 256, 0, stream>>>(flow, bd, bp, ws, cfq, out);
}

// Round 4
// 179.580 us; speedup vs baseline: 2.8558x; 1.2233x over previous
//
#include <hip/hip_runtime.h>
#include <hip/hip_bf16.h>
#include <cstddef>

// ---------------- problem constants ----------------
#define BB   8
#define HH   120
#define WW   160
#define HW   19200          // HH*WW
#define NPIX 153600         // BB*HW
#define CORC 196

#define AS_  ((float)(6.0/127.0))   // ACT_SCALE
#define FS_  0.03125f               // FLOW_SCALE = 3.96875/127 = 2^-5 exactly

// ws layout:
//   float[0]=sd, float[1]=sp, float[2]=s_c1
//   ushort[32 .. 32+21504)      : convc1 B-frags (bf16 int codes), floats 16..10768
//   float[OFF_WF1 .. +128)      : Wf1 dequant
//   float[OFF_WF2 .. +2048)     : Wf2 dequant transposed
//   float[OFF_WD  .. +1152)     : Wd integer codes
//   ushort[OFF_WPQ_US .. +10240): Wp B-frags (bf16 int codes), floats 22160..27280
#define OFF_WF1 18832
#define OFF_WF2 18960
#define OFF_WD  21008
#define OFF_WPQ_US 44320
#define CFQ_BYTE_OFF 131072         // int8 activation buffer, 8*128*19200 bytes

typedef __attribute__((ext_vector_type(8)))  short short8;
typedef __attribute__((ext_vector_type(4)))  float f32x4;

__device__ __forceinline__ float clip127(float x) {
    return fminf(fmaxf(x, -127.f), 127.f);
}

// round-to-nearest-even fp32 -> bf16 (finite inputs only)
__device__ __forceinline__ unsigned short f2bf(float x) {
    unsigned int u = __float_as_uint(x);
    unsigned int r = (u + 0x7fffu + ((u >> 16) & 1u)) >> 16;
    return (unsigned short)r;
}

// ---------------- kernel 0: weight fake-quant ----------------
__global__ __launch_bounds__(256) void quant_weights(
    const float* __restrict__ Wc1, const float* __restrict__ Wf1,
    const float* __restrict__ Wf2, const float* __restrict__ Wd,
    const float* __restrict__ Wp,  float* __restrict__ ws)
{
    __shared__ float red[256];
    const int t = blockIdx.x;
    const float* src = (t == 0) ? Wc1 : (t == 1) ? Wf1 : (t == 2) ? Wf2 : (t == 3) ? Wd : Wp;
    const int n = (t == 0) ? 18816 : (t == 1) ? 128 : (t == 2) ? 2048 : (t == 3) ? 1152 : 10240;
    const int tid = threadIdx.x;

    float m = 0.f;
    for (int i = tid; i < n; i += 256) m = fmaxf(m, fabsf(src[i]));
    red[tid] = m;
    __syncthreads();
    for (int s = 128; s > 0; s >>= 1) {
        if (tid < s) red[tid] = fmaxf(red[tid], red[tid + s]);
        __syncthreads();
    }
    const float s = red[0] / 127.0f + 1e-12f;

    if (t == 0) {
        // convc1 weights as MFMA B-frags: o = nt*16+(l&15), k = kt*32+((l>>4)<<3)+e
        unsigned short* bf = (unsigned short*)ws + 32;
        for (int j = tid; j < 21504; j += 256) {
            const int e    = j & 7;
            const int l    = (j >> 3) & 63;
            const int tile = j >> 9;
            const int nt   = tile % 6;
            const int kt   = tile / 6;
            const int out  = nt * 16 + (l & 15);
            const int k    = kt * 32 + ((l >> 4) << 3) + e;
            float q = 0.f;
            if (k < 196) q = clip127(rintf(Wc1[out * 196 + k] / s));
            bf[j] = f2bf(q);
        }
        if (tid == 0) ws[2] = s;
    } else if (t == 4) {
        // pointwise weights as MFMA B-frags: 5 n-tiles x 4 k-steps
        unsigned short* bf = (unsigned short*)ws + OFF_WPQ_US;
        for (int j = tid; j < 10240; j += 256) {
            const int e    = j & 7;
            const int l    = (j >> 3) & 63;
            const int tile = j >> 9;     // 0..19
            const int nt   = tile % 5;
            const int kt   = tile / 5;
            const int o    = nt * 16 + (l & 15);
            const int k    = kt * 32 + ((l >> 4) << 3) + e;
            const float q  = clip127(rintf(Wp[o * 128 + k] / s));
            bf[j] = f2bf(q);
        }
        if (tid == 0) ws[1] = s;
    } else {
        for (int i = tid; i < n; i += 256) {
            const float q = clip127(rintf(src[i] / s));
            if (t == 1) {            // Wf1 [64][2]
                ws[OFF_WF1 + i] = s * q;
            } else if (t == 2) {     // Wf2 [32][64] -> transposed [64][32]
                int o = i / 64, c = i % 64;
                ws[OFF_WF2 + c * 32 + o] = s * q;
            } else {                 // Wd [128][9]: keep integer q
                ws[OFF_WD + i] = q;
            }
        }
        if (tid == 0 && t == 3) ws[0] = s;
    }
}

// ---------------- kernel 1a: convc1 (196 -> 96) via bf16 MFMA ----------------
#define LDSTRIDE 232
__global__ __launch_bounds__(256) void k1_convc1(
    const float* __restrict__ corr, const float* __restrict__ bc1,
    const float* __restrict__ ws,   signed char* __restrict__ cfq)
{
    __shared__ unsigned short hbuf[64 * LDSTRIDE];
    __shared__ unsigned short lbuf[64 * LDSTRIDE];

    const int tid = threadIdx.x;
    const int p0  = blockIdx.x * 64;
    const int b   = p0 / HW;
    const int hw0 = p0 % HW;
    const float* cp = corr + (size_t)b * CORC * HW + hw0;

    const int pix  = tid & 63;
    const int cgrp = tid >> 6;
    unsigned short* hrow = hbuf + pix * LDSTRIDE;
    unsigned short* lrow = lbuf + pix * LDSTRIDE;

    for (int iter = 0; iter < 13; ++iter) {
        const int c0 = iter * 16 + cgrp * 4;
        unsigned long long hp = 0ull, lp = 0ull;
#pragma unroll
        for (int j = 0; j < 4; ++j) {
            const int c = c0 + j;
            float a = 0.f;
            if (c < 196) a = cp[(size_t)c * HW + pix];
            const unsigned short h = f2bf(a);
            const float hf = __uint_as_float((unsigned int)h << 16);
            const unsigned short lo = f2bf(a - hf);
            hp |= (unsigned long long)h  << (16 * j);
            lp |= (unsigned long long)lo << (16 * j);
        }
        *(unsigned long long*)(hrow + c0) = hp;
        *(unsigned long long*)(lrow + c0) = lp;
    }
    {
        const int c0z = 208 + cgrp * 4;
        *(unsigned long long*)(hrow + c0z) = 0ull;
        *(unsigned long long*)(lrow + c0z) = 0ull;
    }
    __syncthreads();

    const int w = tid >> 6;
    const int l = tid & 63;
    const int arow = w * 16 + (l & 15);
    const int koff = (l >> 4) << 3;
    const unsigned short* hA = hbuf + arow * LDSTRIDE + koff;
    const unsigned short* lA = lbuf + arow * LDSTRIDE + koff;
    const short8* Bfr = (const short8*)((const unsigned short*)ws + 32);

    f32x4 ac0 = {0.f,0.f,0.f,0.f}, ac1 = ac0, ac2 = ac0, ac3 = ac0, ac4 = ac0, ac5 = ac0;

#define NTSTEP(ACC, KT, NT)                                                      \
    {   short8 bq = Bfr[((KT) * 6 + (NT)) * 64 + l];                             \
        ACC = __builtin_amdgcn_mfma_f32_16x16x32_bf16(al_, bq, ACC, 0, 0, 0);    \
        ACC = __builtin_amdgcn_mfma_f32_16x16x32_bf16(ah_, bq, ACC, 0, 0, 0);    }

#pragma unroll
    for (int kt = 0; kt < 7; ++kt) {
        short8 ah_ = *(const short8*)(hA + kt * 32);
        short8 al_ = *(const short8*)(lA + kt * 32);
        NTSTEP(ac0, kt, 0) NTSTEP(ac1, kt, 1) NTSTEP(ac2, kt, 2)
        NTSTEP(ac3, kt, 3) NTSTEP(ac4, kt, 4) NTSTEP(ac5, kt, 5)
    }
#undef NTSTEP

    const float sc1 = ws[2];
    __syncthreads();
    signed char* t8 = (signed char*)hbuf;  // reuse as [96][64] int8

#define EPI(ACC, NT)                                                             \
    {   const int out = (NT) * 16 + (l & 15);                                    \
        const float bias = bc1[out];                                             \
        _Pragma("unroll")                                                        \
        for (int i = 0; i < 4; ++i) {                                            \
            const int prow = w * 16 + ((l >> 4) << 2) + i;                       \
            float v  = fmaf(sc1, ACC[i], bias);                                  \
            float aq = AS_ * clip127(rintf(v / AS_));                            \
            float r  = fmaxf(aq, 0.f);                                           \
            float kk = fminf(rintf(r * 32.f), 127.f);                            \
            float cf = kk * FS_;                                                 \
            float q8 = clip127(rintf(cf / AS_));                                 \
            t8[out * 64 + prow] = (signed char)(int)q8;                          \
        }                                                                        }
    EPI(ac0, 0) EPI(ac1, 1) EPI(ac2, 2) EPI(ac3, 3) EPI(ac4, 4) EPI(ac5, 5)
#undef EPI
    __syncthreads();

    const unsigned int* t32 = (const unsigned int*)t8;
#pragma unroll
    for (int r = 0; r < 6; ++r) {
        const int d   = r * 256 + tid;
        const int out = d >> 4;
        const int pd  = d & 15;
        *(unsigned int*)(cfq + (size_t)(b * 128 + out) * HW + hw0 + pd * 4) = t32[d];
    }
}

// ---------------- kernel 1b: flo path (convf1 2->64, convf2 64->32) ----------------
typedef __attribute__((ext_vector_type(16))) float f32x16;
__global__ __launch_bounds__(256) void k1_flo(
    const float* __restrict__ flow, const float* __restrict__ bf1,
    const float* __restrict__ bf2,  const float* __restrict__ ws,
    signed char* __restrict__ cfq)
{
    const int p  = blockIdx.x * 256 + threadIdx.x;
    const int b  = p / HW;
    const int hw = p % HW;

    const float f0 = flow[(size_t)(b * 2) * HW + hw];
    const float f1 = flow[(size_t)(b * 2 + 1) * HW + hw];

    f32x16 a2a, a2b;
#pragma unroll
    for (int j = 0; j < 16; ++j) { a2a[j] = 0.f; a2b[j] = 0.f; }

    for (int c = 0; c < 64; ++c) {
        const float w0 = ws[OFF_WF1 + 2 * c];
        const float w1 = ws[OFF_WF1 + 2 * c + 1];
        float v  = fmaf(f0, w0, fmaf(f1, w1, bf1[c]));
        float r  = fmaxf(v, 0.f);
        float af = AS_ * fminf(rintf(r / AS_), 127.f);
        const float* w2 = ws + OFF_WF2 + c * 32;
#pragma unroll
        for (int j = 0; j < 16; ++j) {
            a2a[j] = fmaf(af, w2[j],      a2a[j]);
            a2b[j] = fmaf(af, w2[16 + j], a2b[j]);
        }
    }

    signed char* op = cfq + (size_t)b * 128 * HW + (size_t)96 * HW + hw;
#define FLOEPI(ACC, BASE)                                                        \
    _Pragma("unroll")                                                            \
    for (int j = 0; j < 16; ++j) {                                               \
        const int o = (BASE) + j;                                                \
        float v  = ACC[j] + bf2[o];                                              \
        float aq = AS_ * clip127(rintf(v / AS_));                                \
        float r  = fmaxf(aq, 0.f);                                               \
        float kk = fminf(rintf(r * 32.f), 127.f);                                \
        float cf = kk * FS_;                                                     \
        float q8 = clip127(rintf(cf / AS_));                                     \
        op[(size_t)o * HW] = (signed char)(int)q8;                               \
    }
    FLOEPI(a2a, 0) FLOEPI(a2b, 16)
#undef FLOEPI
}

// ---------------- kernel 2: depthwise 3x3 (VALU, exact) + pointwise via MFMA ----------------
// tile = 2 rows x 32 cols = 64 pixels; 4 waves; lane=channel for depthwise.
#define STG_STRIDE 44
__global__ __launch_bounds__(256) void k2_dwpw(
    const float* __restrict__ flow, const float* __restrict__ bd,
    const float* __restrict__ bp,   const float* __restrict__ ws,
    const signed char* __restrict__ cfq, float* __restrict__ out)
{
    __shared__ signed char stage[4 * 128 * STG_STRIDE];   // [row][c][44]
    __shared__ unsigned short afrag[64 * 136];            // [pix][136] bf16 codes

    const int tid = threadIdx.x;
    const int bid = blockIdx.x;
    const int b   = bid / 300;          // 60 row-tiles * 5 col-tiles
    const int rem = bid % 300;
    const int h0  = (rem / 5) * 2;
    const int w0  = (rem % 5) * 32;

    // ---- stage cfq tile + halo: rows h0-1..h0+2, bytes w0-4..w0+39 ----
    for (int j = tid; j < 5120; j += 256) {
        const int i   = j % 10;
        const int c   = (j / 10) % 128;
        const int row = j / 1280;
        const int h   = h0 - 1 + row;
        const int wb  = w0 - 4 + 4 * i;
        unsigned int v = 0u;
        if (h >= 0 && h < HH && wb >= 0 && wb <= WW - 4)
            v = *(const unsigned int*)(cfq + ((size_t)(b * 128 + c) * HW + (size_t)h * WW + wb));
        *(unsigned int*)(stage + (row * 128 + c) * STG_STRIDE + i * 4) = v;
    }
    __syncthreads();

    // ---- depthwise: lane = channel (c0, c0+64), 16 pixels per thread ----
    const int c0 = tid & 63;
    const int pg = tid >> 6;
    const float sd = ws[0], sp = ws[1];
    const float ASsd = AS_ * sd;

    float wd0[9], wd1[9];
#pragma unroll
    for (int t9 = 0; t9 < 9; ++t9) {
        wd0[t9] = ws[OFF_WD + c0 * 9 + t9];
        wd1[t9] = ws[OFF_WD + (c0 + 64) * 9 + t9];
    }
    const float bd0 = bd[c0], bd1 = bd[c0 + 64];

#pragma unroll
    for (int pp = 0; pp < 16; ++pp) {
        const int pix = pg * 16 + pp;
        const int r   = pix >> 5;
        const int col = pix & 31;
        float s0 = 0.f, s1 = 0.f;
#pragma unroll
        for (int dy = 0; dy < 3; ++dy) {
            const int rb = (r + dy) * 128;
            const int xb = 3 + col;
#pragma unroll
            for (int dd = 0; dd < 3; ++dd) {
                s0 = fmaf((float)stage[(rb + c0     ) * STG_STRIDE + xb + dd], wd0[dy * 3 + dd], s0);
                s1 = fmaf((float)stage[(rb + c0 + 64) * STG_STRIDE + xb + dd], wd1[dy * 3 + dd], s1);
            }
        }
        const float q0 = clip127(rintf(fmaf(ASsd, s0, bd0) / AS_));
        const float q1 = clip127(rintf(fmaf(ASsd, s1, bd1) / AS_));
        afrag[pix * 136 + c0]      = f2bf(q0);
        afrag[pix * 136 + c0 + 64] = f2bf(q1);
    }
    __syncthreads();

    // ---- pointwise 128 -> 80 via MFMA: 5 n-tiles x 4 k-steps per wave ----
    const int wv = tid >> 6;
    const int l  = tid & 63;
    const unsigned short* A = afrag + (size_t)(wv * 16 + (l & 15)) * 136 + ((l >> 4) << 3);
    const short8* Bfr = (const short8*)((const unsigned short*)ws + OFF_WPQ_US);

    f32x4 pc0 = {0.f,0.f,0.f,0.f}, pc1 = pc0, pc2 = pc0, pc3 = pc0, pc4 = pc0;

#define PTSTEP(ACC, KT, NT)                                                      \
    {   short8 bq = Bfr[((KT) * 5 + (NT)) * 64 + l];                             \
        ACC = __builtin_amdgcn_mfma_f32_16x16x32_bf16(a_, bq, ACC, 0, 0, 0);     }
#pragma unroll
    for (int kt = 0; kt < 4; ++kt) {
        short8 a_ = *(const short8*)(A + kt * 32);
        PTSTEP(pc0, kt, 0) PTSTEP(pc1, kt, 1) PTSTEP(pc2, kt, 2)
        PTSTEP(pc3, kt, 3) PTSTEP(pc4, kt, 4)
    }
#undef PTSTEP

    // ---- epilogue: quant + direct store (L2 merges the 16-line scatter) ----
    const float ASsp = AS_ * sp;
    float* ob = out + (size_t)b * 82 * HW;

#define PEPI(ACC, NT)                                                            \
    {   const int o = (NT) * 16 + (l & 15);                                      \
        const float bias = bp[o];                                                \
        _Pragma("unroll")                                                        \
        for (int i = 0; i < 4; ++i) {                                            \
            const int pix = wv * 16 + ((l >> 4) << 2) + i;                       \
            const int hw  = (h0 + (pix >> 5)) * WW + w0 + (pix & 31);            \
            float v = fmaf(ASsp, ACC[i], bias);                                  \
            float r = fmaxf(v, 0.f);                                             \
            float k = fminf(rintf(r * 32.f), 127.f);                             \
            ob[(size_t)o * HW + hw] = k * FS_;                                   \
        }                                                                        }
    PEPI(pc0, 0) PEPI(pc1, 1) PEPI(pc2, 2) PEPI(pc3, 3) PEPI(pc4, 4)
#undef PEPI

    // ---- channels 80..81: act_quant(flow, FLOW) ----
    if (tid < 128) {
        const int ch  = tid >> 6;
        const int pix = tid & 63;
        const int hw  = (h0 + (pix >> 5)) * WW + w0 + (pix & 31);
        const float f = flow[(size_t)(b * 2 + ch) * HW + hw];
        const float k = clip127(rintf(f * 32.f));
        ob[(size_t)(80 + ch) * HW + hw] = k * FS_;
    }
}

// ---------------- launcher ----------------
extern "C" void kernel_launch(void* const* d_in, const int* in_sizes, int n_in,
                              void* d_out, int out_size, void* d_ws, size_t ws_size,
                              hipStream_t stream) {
    const float* flow = (const float*)d_in[0];
    const float* corr = (const float*)d_in[1];
    const float* Wc1  = (const float*)d_in[2];
    const float* bc1  = (const float*)d_in[3];
    const float* Wf1  = (const float*)d_in[4];
    const float* bf1  = (const float*)d_in[5];
    const float* Wf2  = (const float*)d_in[6];
    const float* bf2  = (const float*)d_in[7];
    const float* Wd   = (const float*)d_in[8];
    const float* bd   = (const float*)d_in[9];
    const float* Wp   = (const float*)d_in[10];
    const float* bp   = (const float*)d_in[11];

    float* ws = (float*)d_ws;
    signed char* cfq = (signed char*)d_ws + CFQ_BYTE_OFF;
    float* out = (float*)d_out;

    quant_weights<<<5, 256, 0, stream>>>(Wc1, Wf1, Wf2, Wd, Wp, ws);
    k1_convc1<<<NPIX / 64, 256, 0, stream>>>(corr, bc1, ws, cfq);
    k1_flo<<<NPIX / 256, 256, 0, stream>>>(flow, bf1, bf2, ws, cfq);
    k2_dwpw<<<2400, 256, 0, stream>>>(flow, bd, bp, ws, cfq, out);
}

// Round 5
// 159.700 us; speedup vs baseline: 3.2113x; 1.1245x over previous
//
#include <hip/hip_runtime.h>
#include <hip/hip_bf16.h>
#include <cstddef>

// ---------------- problem constants ----------------
#define BB   8
#define HH   120
#define WW   160
#define HW   19200          // HH*WW
#define NPIX 153600         // BB*HW
#define CORC 196

#define AS_  ((float)(6.0/127.0))   // ACT_SCALE
#define FS_  0.03125f               // FLOW_SCALE = 3.96875/127 = 2^-5 exactly

// ws layout:
//   float[0]=sd, float[1]=sp, float[2]=s_c1
//   ushort[32 .. 32+21504)      : convc1 B-frags (bf16 int codes)
//   float[OFF_WF1 .. +128)      : Wf1 dequant
//   float[OFF_WF2 .. +2048)     : Wf2 dequant transposed
//   float[OFF_WD  .. +1152)     : Wd integer codes
//   ushort[OFF_WPQ_US .. +10240): Wp B-frags (bf16 int codes)
#define OFF_WF1 18832
#define OFF_WF2 18960
#define OFF_WD  21008
#define OFF_WPQ_US 44320
#define CFQ_BYTE_OFF 131072         // int8 activation buffer, 8*128*19200 bytes

typedef __attribute__((ext_vector_type(8)))  short short8;
typedef __attribute__((ext_vector_type(4)))  float f32x4;

__device__ __forceinline__ float clip127(float x) {
    return fminf(fmaxf(x, -127.f), 127.f);
}

// round-to-nearest-even fp32 -> bf16 (finite inputs only)
__device__ __forceinline__ unsigned short f2bf(float x) {
    unsigned int u = __float_as_uint(x);
    unsigned int r = (u + 0x7fffu + ((u >> 16) & 1u)) >> 16;
    return (unsigned short)r;
}

// ---------------- kernel 0: weight fake-quant ----------------
__global__ __launch_bounds__(256) void quant_weights(
    const float* __restrict__ Wc1, const float* __restrict__ Wf1,
    const float* __restrict__ Wf2, const float* __restrict__ Wd,
    const float* __restrict__ Wp,  float* __restrict__ ws)
{
    __shared__ float red[256];
    const int t = blockIdx.x;
    const float* src = (t == 0) ? Wc1 : (t == 1) ? Wf1 : (t == 2) ? Wf2 : (t == 3) ? Wd : Wp;
    const int n = (t == 0) ? 18816 : (t == 1) ? 128 : (t == 2) ? 2048 : (t == 3) ? 1152 : 10240;
    const int tid = threadIdx.x;

    float m = 0.f;
    for (int i = tid; i < n; i += 256) m = fmaxf(m, fabsf(src[i]));
    red[tid] = m;
    __syncthreads();
    for (int s = 128; s > 0; s >>= 1) {
        if (tid < s) red[tid] = fmaxf(red[tid], red[tid + s]);
        __syncthreads();
    }
    const float s = red[0] / 127.0f + 1e-12f;

    if (t == 0) {
        // convc1 weights as MFMA B-frags: o = nt*16+(l&15), k = kt*32+((l>>4)<<3)+e
        unsigned short* bf = (unsigned short*)ws + 32;
        for (int j = tid; j < 21504; j += 256) {
            const int e    = j & 7;
            const int l    = (j >> 3) & 63;
            const int tile = j >> 9;
            const int nt   = tile % 6;
            const int kt   = tile / 6;
            const int out  = nt * 16 + (l & 15);
            const int k    = kt * 32 + ((l >> 4) << 3) + e;
            float q = 0.f;
            if (k < 196) q = clip127(rintf(Wc1[out * 196 + k] / s));
            bf[j] = f2bf(q);
        }
        if (tid == 0) ws[2] = s;
    } else if (t == 4) {
        // pointwise weights as MFMA B-frags: 5 n-tiles x 4 k-steps
        unsigned short* bf = (unsigned short*)ws + OFF_WPQ_US;
        for (int j = tid; j < 10240; j += 256) {
            const int e    = j & 7;
            const int l    = (j >> 3) & 63;
            const int tile = j >> 9;     // 0..19
            const int nt   = tile % 5;
            const int kt   = tile / 5;
            const int o    = nt * 16 + (l & 15);
            const int k    = kt * 32 + ((l >> 4) << 3) + e;
            const float q  = clip127(rintf(Wp[o * 128 + k] / s));
            bf[j] = f2bf(q);
        }
        if (tid == 0) ws[1] = s;
    } else {
        for (int i = tid; i < n; i += 256) {
            const float q = clip127(rintf(src[i] / s));
            if (t == 1) {            // Wf1 [64][2]
                ws[OFF_WF1 + i] = s * q;
            } else if (t == 2) {     // Wf2 [32][64] -> transposed [64][32]
                int o = i / 64, c = i % 64;
                ws[OFF_WF2 + c * 32 + o] = s * q;
            } else {                 // Wd [128][9]: keep integer q
                ws[OFF_WD + i] = q;
            }
        }
        if (tid == 0 && t == 3) ws[0] = s;
    }
}

// ---------------- kernel 1a: convc1 (196 -> 96) via bf16 MFMA, direct A loads ----
// 128 pixels/block, 4 waves; wave w owns pixels [w*32, w*32+32) as two 16-row m-tiles.
// A-fragments loaded per-lane straight from corr (L3-resident), hi/lo bf16 split in regs.
#define TSTRIDE 136   // t8 row stride (bytes): 34 dwords, odd*2 -> 2-way max on LDS
__global__ __launch_bounds__(256, 4) void k1_convc1(
    const float* __restrict__ corr, const float* __restrict__ bc1,
    const float* __restrict__ ws,   signed char* __restrict__ cfq)
{
    __shared__ signed char t8[96 * TSTRIDE];   // transpose buffer [96 out][128 pix]

    const int tid = threadIdx.x;
    const int w   = tid >> 6;
    const int l   = tid & 63;
    const int p0  = blockIdx.x * 128;          // 19200 % 128 == 0 -> no batch straddle
    const int b   = p0 / HW;
    const int hw0 = p0 % HW;
    const float* cp = corr + (size_t)b * CORC * HW + hw0;

    const int r0   = w * 32 + (l & 15);        // m-tile 0 pixel row
    const int koff = (l >> 4) << 3;            // k sub-offset within 32-k step
    const short8* Bfr = (const short8*)((const unsigned short*)ws + 32);

    f32x4 a00 = {0.f,0.f,0.f,0.f}, a01 = a00, a02 = a00, a03 = a00, a04 = a00, a05 = a00;
    f32x4 a10 = a00, a11 = a00, a12 = a00, a13 = a00, a14 = a00, a15 = a00;

#pragma unroll
    for (int kt = 0; kt < 7; ++kt) {
        // per-lane direct loads: 8 channels x 2 pixel tiles
        short8 h0_, l0_, h1_, l1_;
#pragma unroll
        for (int e = 0; e < 8; ++e) {
            const int c = kt * 32 + koff + e;
            float v0 = 0.f, v1 = 0.f;
            if (c < CORC) {
                const float* pc = cp + (size_t)c * HW;
                v0 = pc[r0];
                v1 = pc[r0 + 16];
            }
            const unsigned short h0 = f2bf(v0);
            const unsigned short h1 = f2bf(v1);
            h0_[e] = (short)h0;
            h1_[e] = (short)h1;
            l0_[e] = (short)f2bf(v0 - __uint_as_float((unsigned int)h0 << 16));
            l1_[e] = (short)f2bf(v1 - __uint_as_float((unsigned int)h1 << 16));
        }
#define NTSTEP(A0, A1, NT)                                                        \
        {   short8 bq = Bfr[((kt) * 6 + (NT)) * 64 + l];                          \
            A0 = __builtin_amdgcn_mfma_f32_16x16x32_bf16(l0_, bq, A0, 0, 0, 0);   \
            A0 = __builtin_amdgcn_mfma_f32_16x16x32_bf16(h0_, bq, A0, 0, 0, 0);   \
            A1 = __builtin_amdgcn_mfma_f32_16x16x32_bf16(l1_, bq, A1, 0, 0, 0);   \
            A1 = __builtin_amdgcn_mfma_f32_16x16x32_bf16(h1_, bq, A1, 0, 0, 0);   }
        NTSTEP(a00, a10, 0) NTSTEP(a01, a11, 1) NTSTEP(a02, a12, 2)
        NTSTEP(a03, a13, 3) NTSTEP(a04, a14, 4) NTSTEP(a05, a15, 5)
#undef NTSTEP
    }

    // ---- epilogue: quant chain -> t8 transpose buffer ----
    const float sc1 = ws[2];

#define EPI(ACC, NT, TILE)                                                        \
    {   const int out = (NT) * 16 + (l & 15);                                     \
        const float bias = bc1[out];                                              \
        _Pragma("unroll")                                                         \
        for (int i = 0; i < 4; ++i) {                                             \
            const int prow = w * 32 + (TILE) * 16 + ((l >> 4) << 2) + i;          \
            float v  = fmaf(sc1, ACC[i], bias);                                   \
            float aq = AS_ * clip127(rintf(v / AS_));                             \
            float r  = fmaxf(aq, 0.f);                                            \
            float kk = fminf(rintf(r * 32.f), 127.f);                             \
            float cf = kk * FS_;                                                  \
            float q8 = clip127(rintf(cf / AS_));                                  \
            t8[out * TSTRIDE + prow] = (signed char)(int)q8;                      \
        }                                                                         }
    EPI(a00, 0, 0) EPI(a01, 1, 0) EPI(a02, 2, 0) EPI(a03, 3, 0) EPI(a04, 4, 0) EPI(a05, 5, 0)
    EPI(a10, 0, 1) EPI(a11, 1, 1) EPI(a12, 2, 1) EPI(a13, 3, 1) EPI(a14, 4, 1) EPI(a15, 5, 1)
#undef EPI
    __syncthreads();

    // ---- coalesced store: 96 rows x 128 bytes ----
#pragma unroll
    for (int r = 0; r < 12; ++r) {
        const int d   = r * 256 + tid;     // 3072 dwords total
        const int out = d >> 5;
        const int pd  = d & 31;
        const unsigned int v = *(const unsigned int*)(t8 + out * TSTRIDE + pd * 4);
        *(unsigned int*)(cfq + (size_t)(b * 128 + out) * HW + hw0 + pd * 4) = v;
    }
}

// ---------------- kernel 1b: flo path (convf1 2->64, convf2 64->32) ----------------
typedef __attribute__((ext_vector_type(16))) float f32x16;
__global__ __launch_bounds__(256) void k1_flo(
    const float* __restrict__ flow, const float* __restrict__ bf1,
    const float* __restrict__ bf2,  const float* __restrict__ ws,
    signed char* __restrict__ cfq)
{
    const int p  = blockIdx.x * 256 + threadIdx.x;
    const int b  = p / HW;
    const int hw = p % HW;

    const float f0 = flow[(size_t)(b * 2) * HW + hw];
    const float f1 = flow[(size_t)(b * 2 + 1) * HW + hw];

    f32x16 a2a, a2b;
#pragma unroll
    for (int j = 0; j < 16; ++j) { a2a[j] = 0.f; a2b[j] = 0.f; }

    for (int c = 0; c < 64; ++c) {
        const float w0 = ws[OFF_WF1 + 2 * c];
        const float w1 = ws[OFF_WF1 + 2 * c + 1];
        float v  = fmaf(f0, w0, fmaf(f1, w1, bf1[c]));
        float r  = fmaxf(v, 0.f);
        float af = AS_ * fminf(rintf(r / AS_), 127.f);
        const float* w2 = ws + OFF_WF2 + c * 32;
#pragma unroll
        for (int j = 0; j < 16; ++j) {
            a2a[j] = fmaf(af, w2[j],      a2a[j]);
            a2b[j] = fmaf(af, w2[16 + j], a2b[j]);
        }
    }

    signed char* op = cfq + (size_t)b * 128 * HW + (size_t)96 * HW + hw;
#define FLOEPI(ACC, BASE)                                                        \
    _Pragma("unroll")                                                            \
    for (int j = 0; j < 16; ++j) {                                               \
        const int o = (BASE) + j;                                                \
        float v  = ACC[j] + bf2[o];                                              \
        float aq = AS_ * clip127(rintf(v / AS_));                                \
        float r  = fmaxf(aq, 0.f);                                               \
        float kk = fminf(rintf(r * 32.f), 127.f);                                \
        float cf = kk * FS_;                                                     \
        float q8 = clip127(rintf(cf / AS_));                                     \
        op[(size_t)o * HW] = (signed char)(int)q8;                               \
    }
    FLOEPI(a2a, 0) FLOEPI(a2b, 16)
#undef FLOEPI
}

// ---------------- kernel 2: depthwise 3x3 (VALU, exact) + pointwise via MFMA ----------------
#define STG_STRIDE 44
__global__ __launch_bounds__(256) void k2_dwpw(
    const float* __restrict__ flow, const float* __restrict__ bd,
    const float* __restrict__ bp,   const float* __restrict__ ws,
    const signed char* __restrict__ cfq, float* __restrict__ out)
{
    __shared__ signed char stage[4 * 128 * STG_STRIDE];   // [row][c][44]
    __shared__ unsigned short afrag[64 * 136];            // [pix][136] bf16 codes

    const int tid = threadIdx.x;
    const int bid = blockIdx.x;
    const int b   = bid / 300;          // 60 row-tiles * 5 col-tiles
    const int rem = bid % 300;
    const int h0  = (rem / 5) * 2;
    const int w0  = (rem % 5) * 32;

    for (int j = tid; j < 5120; j += 256) {
        const int i   = j % 10;
        const int c   = (j / 10) % 128;
        const int row = j / 1280;
        const int h   = h0 - 1 + row;
        const int wb  = w0 - 4 + 4 * i;
        unsigned int v = 0u;
        if (h >= 0 && h < HH && wb >= 0 && wb <= WW - 4)
            v = *(const unsigned int*)(cfq + ((size_t)(b * 128 + c) * HW + (size_t)h * WW + wb));
        *(unsigned int*)(stage + (row * 128 + c) * STG_STRIDE + i * 4) = v;
    }
    __syncthreads();

    const int c0 = tid & 63;
    const int pg = tid >> 6;
    const float sd = ws[0], sp = ws[1];
    const float ASsd = AS_ * sd;

    float wd0[9], wd1[9];
#pragma unroll
    for (int t9 = 0; t9 < 9; ++t9) {
        wd0[t9] = ws[OFF_WD + c0 * 9 + t9];
        wd1[t9] = ws[OFF_WD + (c0 + 64) * 9 + t9];
    }
    const float bd0 = bd[c0], bd1 = bd[c0 + 64];

#pragma unroll
    for (int pp = 0; pp < 16; ++pp) {
        const int pix = pg * 16 + pp;
        const int r   = pix >> 5;
        const int col = pix & 31;
        float s0 = 0.f, s1 = 0.f;
#pragma unroll
        for (int dy = 0; dy < 3; ++dy) {
            const int rb = (r + dy) * 128;
            const int xb = 3 + col;
#pragma unroll
            for (int dd = 0; dd < 3; ++dd) {
                s0 = fmaf((float)stage[(rb + c0     ) * STG_STRIDE + xb + dd], wd0[dy * 3 + dd], s0);
                s1 = fmaf((float)stage[(rb + c0 + 64) * STG_STRIDE + xb + dd], wd1[dy * 3 + dd], s1);
            }
        }
        const float q0 = clip127(rintf(fmaf(ASsd, s0, bd0) / AS_));
        const float q1 = clip127(rintf(fmaf(ASsd, s1, bd1) / AS_));
        afrag[pix * 136 + c0]      = f2bf(q0);
        afrag[pix * 136 + c0 + 64] = f2bf(q1);
    }
    __syncthreads();

    const int wv = tid >> 6;
    const int l  = tid & 63;
    const unsigned short* A = afrag + (size_t)(wv * 16 + (l & 15)) * 136 + ((l >> 4) << 3);
    const short8* Bfr = (const short8*)((const unsigned short*)ws + OFF_WPQ_US);

    f32x4 pc0 = {0.f,0.f,0.f,0.f}, pc1 = pc0, pc2 = pc0, pc3 = pc0, pc4 = pc0;

#define PTSTEP(ACC, KT, NT)                                                      \
    {   short8 bq = Bfr[((KT) * 5 + (NT)) * 64 + l];                             \
        ACC = __builtin_amdgcn_mfma_f32_16x16x32_bf16(a_, bq, ACC, 0, 0, 0);     }
#pragma unroll
    for (int kt = 0; kt < 4; ++kt) {
        short8 a_ = *(const short8*)(A + kt * 32);
        PTSTEP(pc0, kt, 0) PTSTEP(pc1, kt, 1) PTSTEP(pc2, kt, 2)
        PTSTEP(pc3, kt, 3) PTSTEP(pc4, kt, 4)
    }
#undef PTSTEP

    const float ASsp = AS_ * sp;
    float* ob = out + (size_t)b * 82 * HW;

#define PEPI(ACC, NT)                                                            \
    {   const int o = (NT) * 16 + (l & 15);                                      \
        const float bias = bp[o];                                                \
        _Pragma("unroll")                                                        \
        for (int i = 0; i < 4; ++i) {                                            \
            const int pix = wv * 16 + ((l >> 4) << 2) + i;                       \
            const int hw  = (h0 + (pix >> 5)) * WW + w0 + (pix & 31);            \
            float v = fmaf(ASsp, ACC[i], bias);                                  \
            float r = fmaxf(v, 0.f);                                             \
            float k = fminf(rintf(r * 32.f), 127.f);                             \
            ob[(size_t)o * HW + hw] = k * FS_;                                   \
        }                                                                        }
    PEPI(pc0, 0) PEPI(pc1, 1) PEPI(pc2, 2) PEPI(pc3, 3) PEPI(pc4, 4)
#undef PEPI

    if (tid < 128) {
        const int ch  = tid >> 6;
        const int pix = tid & 63;
        const int hw  = (h0 + (pix >> 5)) * WW + w0 + (pix & 31);
        const float f = flow[(size_t)(b * 2 + ch) * HW + hw];
        const float k = clip127(rintf(f * 32.f));
        ob[(size_t)(80 + ch) * HW + hw] = k * FS_;
    }
}

// ---------------- launcher ----------------
extern "C" void kernel_launch(void* const* d_in, const int* in_sizes, int n_in,
                              void* d_out, int out_size, void* d_ws, size_t ws_size,
                              hipStream_t stream) {
    const float* flow = (const float*)d_in[0];
    const float* corr = (const float*)d_in[1];
    const float* Wc1  = (const float*)d_in[2];
    const float* bc1  = (const float*)d_in[3];
    const float* Wf1  = (const float*)d_in[4];
    const float* bf1  = (const float*)d_in[5];
    const float* Wf2  = (const float*)d_in[6];
    const float* bf2  = (const float*)d_in[7];
    const float* Wd   = (const float*)d_in[8];
    const float* bd   = (const float*)d_in[9];
    const float* Wp   = (const float*)d_in[10];
    const float* bp   = (const float*)d_in[11];

    float* ws = (float*)d_ws;
    signed char* cfq = (signed char*)d_ws + CFQ_BYTE_OFF;
    float* out = (float*)d_out;

    quant_weights<<<5, 256, 0, stream>>>(Wc1, Wf1, Wf2, Wd, Wp, ws);
    k1_convc1<<<NPIX / 128, 256, 0, stream>>>(corr, bc1, ws, cfq);
    k1_flo<<<NPIX / 256, 256, 0, stream>>>(flow, bf1, bf2, ws, cfq);
    k2_dwpw<<<2400, 256, 0, stream>>>(flow, bd, bp, ws, cfq, out);
}